// Round 1
// baseline (557.353 us; speedup 1.0000x reference)
//
#include <hip/hip_runtime.h>

#define Bn 8
#define Nn 2000
#define Gn 100
#define Hm 320
#define Wm 320
#define NUM_POS 66
#define NUM_NEG 134
#define TRAIN_ROIS 200
#define MASK_H 28
#define MASK_W 28
#define EPSf 1e-8f

// ---------------- kernel 1: per-proposal max IoU + argmax over GT ----------------
__global__ void k_iou(const float* __restrict__ proposals,
                      const float* __restrict__ gt_boxes,
                      const unsigned int* __restrict__ masks_raw,
                      float* __restrict__ ws_m, int* __restrict__ ws_g,
                      int* __restrict__ flag) {
#pragma clang fp contract(off)
    int b = blockIdx.x;
    int tid = threadIdx.x;
    __shared__ float4 sgt[Gn];
    __shared__ unsigned char svalid[Gn];
    for (int g = tid; g < Gn; g += blockDim.x) {
        const float* q = gt_boxes + (b * Gn + g) * 4;
        float4 bx = make_float4(q[0], q[1], q[2], q[3]);
        sgt[g] = bx;
        svalid[g] = (fabsf(bx.x) > 0.f) || (fabsf(bx.y) > 0.f) ||
                    (fabsf(bx.z) > 0.f) || (fabsf(bx.w) > 0.f);
    }
    // dtype probe for prior_masks: 0 = int32, 1 = uint8(bool bytes), 2 = float32
    if (b == 0 && tid == 0) {
        int f = 0;
        for (int i = 0; i < 64; ++i) {
            unsigned int w = masks_raw[i];
            if (w == 0x3F800000u) { f = 2; break; }
            if (w > 1u) f = 1;
        }
        *flag = f;
    }
    __syncthreads();
    for (int i = tid; i < Nn; i += blockDim.x) {
        const float* pp = proposals + (b * Nn + i) * 4;
        float p0 = pp[0], p1 = pp[1], p2 = pp[2], p3 = pp[3];
        bool vp = (fabsf(p0) > 0.f) || (fabsf(p1) > 0.f) ||
                  (fabsf(p2) > 0.f) || (fabsf(p3) > 0.f);
        float area_a = (p2 - p0) * (p3 - p1);
        float m = -1.0f;
        int best = 0;
        for (int g = 0; g < Gn; ++g) {
            float val = -1.0f;
            if (vp && svalid[g]) {
                float4 q = sgt[g];
                float y1 = fmaxf(p0, q.x);
                float x1 = fmaxf(p1, q.y);
                float y2 = fminf(p2, q.z);
                float x2 = fminf(p3, q.w);
                float inter = fmaxf(y2 - y1, 0.f) * fmaxf(x2 - x1, 0.f);
                float area_b = (q.z - q.x) * (q.w - q.y);
                float uni = area_a + area_b - inter;
                val = inter / fmaxf(uni, EPSf);
            }
            if (val > m) { m = val; best = g; }  // strict > == first-index argmax
        }
        ws_m[b * Nn + i] = m;
        ws_g[b * Nn + i] = best;
    }
}

// ---------------- kernel 2: sort + select + rois/class/deltas ----------------
__global__ __launch_bounds__(1024) void k_select(
        const float* __restrict__ proposals,
        const int* __restrict__ class_ids,
        const float* __restrict__ gt_boxes,
        const float* __restrict__ ws_m,
        const int* __restrict__ ws_g,
        int* __restrict__ posmap,
        float* __restrict__ out) {
#pragma clang fp contract(off)
    int b = blockIdx.x;
    int tid = threadIdx.x;
    __shared__ unsigned long long key[2048];
    __shared__ int cnt_pos, cnt_neg;
    if (tid == 0) { cnt_pos = 0; cnt_neg = 0; }
    __syncthreads();
    for (int i = tid; i < 2048; i += 1024) {
        unsigned long long k;
        if (i < Nn) {
            float m = ws_m[b * Nn + i];
            if (m >= 0.5f) atomicAdd(&cnt_pos, 1);
            else if (m >= 0.0f) atomicAdd(&cnt_neg, 1);  // valid prop, neg
            unsigned int u = __float_as_uint(m);
            u = (u & 0x80000000u) ? ~u : (u | 0x80000000u);  // monotone map
            k = ((unsigned long long)u << 32) | (unsigned int)(~(unsigned int)i);
        } else {
            k = 0ull;  // pad sorts last
        }
        key[i] = k;
    }
    __syncthreads();
    // bitonic sort, descending; ties break to lower index via ~i low bits
    for (int kk = 2; kk <= 2048; kk <<= 1) {
        for (int j = kk >> 1; j > 0; j >>= 1) {
            for (int i = tid; i < 2048; i += 1024) {
                int ixj = i ^ j;
                if (ixj > i) {
                    bool desc = ((i & kk) == 0);
                    unsigned long long a = key[i], c = key[ixj];
                    if ((a < c) == desc) { key[i] = c; key[ixj] = a; }
                }
            }
            __syncthreads();
        }
    }
    int cp = cnt_pos, cn = cnt_neg;
    int pos_count = min(cp, NUM_POS);
    // replicate float32: (pos/0.33f) truncated to int, minus pos
    int nc = (int)((float)pos_count / 0.33f) - pos_count;
    nc = min(nc, cn);
    nc = min(nc, NUM_NEG);

    float* rois = out;                                   // [B][200][4]
    float* tcls = out + Bn * TRAIN_ROIS * 4;             // [B][200]
    float* tdel = tcls + Bn * TRAIN_ROIS;                // [B][200][4]

    if (tid < TRAIN_ROIS) {
        int s = tid;
        float r0 = 0, r1 = 0, r2 = 0, r3 = 0, cls = 0;
        float d0 = 0, d1 = 0, d2 = 0, d3 = 0;
        if (s < NUM_POS) {
            int pi = -1, pg = -1;
            if (s < pos_count) {
                int i = (int)(~(unsigned int)key[s]);
                int g = ws_g[b * Nn + i];
                pi = i; pg = g;
                const float* p = proposals + (b * Nn + i) * 4;
                const float* q = gt_boxes + (b * Gn + g) * 4;
                r0 = p[0]; r1 = p[1]; r2 = p[2]; r3 = p[3];
                cls = (float)class_ids[b * Gn + g];
                float h = fmaxf(p[2] - p[0], EPSf);
                float w = fmaxf(p[3] - p[1], EPSf);
                float cy = p[0] + 0.5f * h, cx = p[1] + 0.5f * w;
                float gh = fmaxf(q[2] - q[0], EPSf);
                float gw = fmaxf(q[3] - q[1], EPSf);
                float gcy = q[0] + 0.5f * gh, gcx = q[1] + 0.5f * gw;
                d0 = ((gcy - cy) / h) / 0.1f;
                d1 = ((gcx - cx) / w) / 0.1f;
                d2 = logf(gh / h) / 0.2f;
                d3 = logf(gw / w) / 0.2f;
            }
            posmap[(b * NUM_POS + s) * 2 + 0] = pi;
            posmap[(b * NUM_POS + s) * 2 + 1] = pg;
        } else {
            int j = s - NUM_POS;
            if (j < nc) {
                // negatives start right after ALL cp positives in the combined sort
                int i = (int)(~(unsigned int)key[cp + j]);
                const float* p = proposals + (b * Nn + i) * 4;
                r0 = p[0]; r1 = p[1]; r2 = p[2]; r3 = p[3];
            }
        }
        float* ro = rois + (b * TRAIN_ROIS + s) * 4;
        ro[0] = r0; ro[1] = r1; ro[2] = r2; ro[3] = r3;
        tcls[b * TRAIN_ROIS + s] = cls;
        float* dd = tdel + (b * TRAIN_ROIS + s) * 4;
        dd[0] = d0; dd[1] = d1; dd[2] = d2; dd[3] = d3;
    }
}

// ---------------- kernel 3: bilinear crop-resize of GT masks ----------------
__global__ void k_mask(const float* __restrict__ proposals,
                       const void* __restrict__ masks,
                       const int* __restrict__ posmap,
                       const int* __restrict__ flag,
                       float* __restrict__ out_mask) {
#pragma clang fp contract(off)
    int s = blockIdx.x;   // 0..199
    int b = blockIdx.y;
    float* o = out_mask + (long long)(b * TRAIN_ROIS + s) * (MASK_H * MASK_W);
    int pi = -1, pg = 0;
    if (s < NUM_POS) {
        pi = posmap[(b * NUM_POS + s) * 2 + 0];
        pg = posmap[(b * NUM_POS + s) * 2 + 1];
    }
    if (pi < 0) {
        for (int p = threadIdx.x; p < MASK_H * MASK_W; p += blockDim.x) o[p] = 0.f;
        return;
    }
    int f = *flag;
    const float* box = proposals + (b * Nn + pi) * 4;
    float y1 = box[0], x1 = box[1], y2 = box[2], x2 = box[3];
    for (int p = threadIdx.x; p < MASK_H * MASK_W; p += blockDim.x) {
        int py = p / MASK_W, px = p % MASK_W;
        float fy = (float)py / (float)(MASK_H - 1);
        float fx = (float)px / (float)(MASK_W - 1);
        float ys = y1 * (float)(Hm - 1) + (fy * (y2 - y1)) * (float)(Hm - 1);
        ys = fminf(fmaxf(ys, 0.f), (float)(Hm - 1));
        float xs = x1 * (float)(Wm - 1) + (fx * (x2 - x1)) * (float)(Wm - 1);
        xs = fminf(fmaxf(xs, 0.f), (float)(Wm - 1));
        int y0 = min(max((int)floorf(ys), 0), Hm - 2);
        int x0 = min(max((int)floorf(xs), 0), Wm - 2);
        float wy = ys - (float)y0;
        float wx = xs - (float)x0;
        long long i00 = ((long long)(b * Hm + y0) * Wm + x0) * Gn + pg;
        long long i01 = i00 + Gn;
        long long i10 = i00 + (long long)Wm * Gn;
        long long i11 = i10 + Gn;
        float c00, c01, c10, c11;
        if (f == 0) {
            const int* mi = (const int*)masks;
            c00 = (float)mi[i00]; c01 = (float)mi[i01];
            c10 = (float)mi[i10]; c11 = (float)mi[i11];
        } else if (f == 1) {
            const unsigned char* mu = (const unsigned char*)masks;
            c00 = (float)mu[i00]; c01 = (float)mu[i01];
            c10 = (float)mu[i10]; c11 = (float)mu[i11];
        } else {
            const float* mf = (const float*)masks;
            c00 = mf[i00]; c01 = mf[i01];
            c10 = mf[i10]; c11 = mf[i11];
        }
        float top = c00 * (1.f - wx) + c01 * wx;
        float bot = c10 * (1.f - wx) + c11 * wx;
        float v = top * (1.f - wy) + bot * wy;
        o[p] = rintf(v);   // round half to even == jnp.round
    }
}

extern "C" void kernel_launch(void* const* d_in, const int* in_sizes, int n_in,
                              void* d_out, int out_size, void* d_ws, size_t ws_size,
                              hipStream_t stream) {
    const float* proposals = (const float*)d_in[0];
    const int* class_ids = (const int*)d_in[1];
    const float* gt_boxes = (const float*)d_in[2];
    const void* masks = d_in[3];
    float* out = (float*)d_out;

    char* ws = (char*)d_ws;
    float* ws_m = (float*)ws;                                  // B*N floats
    int* ws_g = (int*)(ws + Bn * Nn * 4);                      // B*N ints
    int* posmap = (int*)(ws + 2 * Bn * Nn * 4);                // B*66*2 ints
    int* flag = (int*)(ws + 2 * Bn * Nn * 4 + Bn * NUM_POS * 2 * 4);

    k_iou<<<dim3(Bn), 256, 0, stream>>>(proposals, gt_boxes,
                                        (const unsigned int*)masks,
                                        ws_m, ws_g, flag);
    k_select<<<dim3(Bn), 1024, 0, stream>>>(proposals, class_ids, gt_boxes,
                                            ws_m, ws_g, posmap, out);
    float* out_mask = out + Bn * TRAIN_ROIS * 4 + Bn * TRAIN_ROIS + Bn * TRAIN_ROIS * 4;
    k_mask<<<dim3(TRAIN_ROIS, Bn), 256, 0, stream>>>(proposals, masks, posmap,
                                                     flag, out_mask);
}

// Round 2
// 472.048 us; speedup vs baseline: 1.1807x; 1.1807x over previous
//
#include <hip/hip_runtime.h>

#define Bn 8
#define Nn 2000
#define Gn 100
#define Hm 320
#define Wm 320
#define NUM_POS 66
#define NUM_NEG 134
#define TRAIN_ROIS 200
#define MASK_H 28
#define MASK_W 28
#define EPSf 1e-8f

// ---- fused kernel: IoU + argmax + bitonic top-k + rois/class/deltas ----
__global__ __launch_bounds__(1024) void k_select(
        const float* __restrict__ proposals,
        const int* __restrict__ class_ids,
        const float* __restrict__ gt_boxes,
        const unsigned int* __restrict__ masks_raw,
        int* __restrict__ posmap,
        int* __restrict__ flag,
        float* __restrict__ out) {
#pragma clang fp contract(off)
    int b = blockIdx.x;
    int tid = threadIdx.x;
    __shared__ unsigned long long key[2048];
    __shared__ unsigned char g_arr[2048];
    __shared__ float4 sgt[Gn];
    __shared__ unsigned char svalid[Gn];
    __shared__ int cnt_pos, cnt_neg;
    if (tid == 0) { cnt_pos = 0; cnt_neg = 0; }
    for (int g = tid; g < Gn; g += 1024) {
        const float* q = gt_boxes + (b * Gn + g) * 4;
        float4 bx = make_float4(q[0], q[1], q[2], q[3]);
        sgt[g] = bx;
        svalid[g] = (fabsf(bx.x) > 0.f) || (fabsf(bx.y) > 0.f) ||
                    (fabsf(bx.z) > 0.f) || (fabsf(bx.w) > 0.f);
    }
    // dtype probe for prior_masks: 0 = int32, 1 = uint8(bool bytes), 2 = float32
    if (b == 0 && tid == 0) {
        int f = 0;
        for (int i = 0; i < 64; ++i) {
            unsigned int w = masks_raw[i];
            if (w == 0x3F800000u) { f = 2; break; }
            if (w > 1u) f = 1;
        }
        *flag = f;
    }
    __syncthreads();
    // per-proposal max IoU + argmax straight into sort keys
    for (int i = tid; i < 2048; i += 1024) {
        unsigned long long k = 0ull;  // pad sorts last
        if (i < Nn) {
            const float* pp = proposals + (b * Nn + i) * 4;
            float p0 = pp[0], p1 = pp[1], p2 = pp[2], p3 = pp[3];
            bool vp = (fabsf(p0) > 0.f) || (fabsf(p1) > 0.f) ||
                      (fabsf(p2) > 0.f) || (fabsf(p3) > 0.f);
            float area_a = (p2 - p0) * (p3 - p1);
            float m = -1.0f;
            int best = 0;
            for (int g = 0; g < Gn; ++g) {
                float val = -1.0f;
                if (vp && svalid[g]) {
                    float4 q = sgt[g];
                    float y1 = fmaxf(p0, q.x);
                    float x1 = fmaxf(p1, q.y);
                    float y2 = fminf(p2, q.z);
                    float x2 = fminf(p3, q.w);
                    float inter = fmaxf(y2 - y1, 0.f) * fmaxf(x2 - x1, 0.f);
                    float area_b = (q.z - q.x) * (q.w - q.y);
                    float uni = area_a + area_b - inter;
                    val = inter / fmaxf(uni, EPSf);
                }
                if (val > m) { m = val; best = g; }  // strict > == first-index argmax
            }
            g_arr[i] = (unsigned char)best;
            if (m >= 0.5f) atomicAdd(&cnt_pos, 1);
            else if (m >= 0.0f) atomicAdd(&cnt_neg, 1);  // valid prop, neg
            unsigned int u = __float_as_uint(m);
            u = (u & 0x80000000u) ? ~u : (u | 0x80000000u);  // monotone map
            k = ((unsigned long long)u << 32) | (unsigned int)(~(unsigned int)i);
        }
        key[i] = k;
    }
    __syncthreads();
    // bitonic sort, descending; ties break to lower index via ~i low bits
    for (int kk = 2; kk <= 2048; kk <<= 1) {
        for (int j = kk >> 1; j > 0; j >>= 1) {
            for (int i = tid; i < 2048; i += 1024) {
                int ixj = i ^ j;
                if (ixj > i) {
                    bool desc = ((i & kk) == 0);
                    unsigned long long a = key[i], c = key[ixj];
                    if ((a < c) == desc) { key[i] = c; key[ixj] = a; }
                }
            }
            __syncthreads();
        }
    }
    int cp = cnt_pos, cn = cnt_neg;
    int pos_count = min(cp, NUM_POS);
    // replicate float32: (pos/0.33f) truncated to int, minus pos
    int nc = (int)((float)pos_count / 0.33f) - pos_count;
    nc = min(nc, cn);
    nc = min(nc, NUM_NEG);

    float* rois = out;                                   // [B][200][4]
    float* tcls = out + Bn * TRAIN_ROIS * 4;             // [B][200]
    float* tdel = tcls + Bn * TRAIN_ROIS;                // [B][200][4]

    if (tid < TRAIN_ROIS) {
        int s = tid;
        float r0 = 0, r1 = 0, r2 = 0, r3 = 0, cls = 0;
        float d0 = 0, d1 = 0, d2 = 0, d3 = 0;
        if (s < NUM_POS) {
            int pi = -1, pg = -1;
            if (s < pos_count) {
                int i = (int)(~(unsigned int)key[s]);
                int g = (int)g_arr[i];
                pi = i; pg = g;
                const float* p = proposals + (b * Nn + i) * 4;
                const float* q = gt_boxes + (b * Gn + g) * 4;
                r0 = p[0]; r1 = p[1]; r2 = p[2]; r3 = p[3];
                cls = (float)class_ids[b * Gn + g];
                float h = fmaxf(p[2] - p[0], EPSf);
                float w = fmaxf(p[3] - p[1], EPSf);
                float cy = p[0] + 0.5f * h, cx = p[1] + 0.5f * w;
                float gh = fmaxf(q[2] - q[0], EPSf);
                float gw = fmaxf(q[3] - q[1], EPSf);
                float gcy = q[0] + 0.5f * gh, gcx = q[1] + 0.5f * gw;
                d0 = ((gcy - cy) / h) / 0.1f;
                d1 = ((gcx - cx) / w) / 0.1f;
                d2 = logf(gh / h) / 0.2f;
                d3 = logf(gw / w) / 0.2f;
            }
            posmap[(b * NUM_POS + s) * 2 + 0] = pi;
            posmap[(b * NUM_POS + s) * 2 + 1] = pg;
        } else {
            int j = s - NUM_POS;
            if (j < nc) {
                // negatives start right after ALL cp positives in the combined sort
                int i = (int)(~(unsigned int)key[cp + j]);
                const float* p = proposals + (b * Nn + i) * 4;
                r0 = p[0]; r1 = p[1]; r2 = p[2]; r3 = p[3];
            }
        }
        float* ro = rois + (b * TRAIN_ROIS + s) * 4;
        ro[0] = r0; ro[1] = r1; ro[2] = r2; ro[3] = r3;
        tcls[b * TRAIN_ROIS + s] = cls;
        float* dd = tdel + (b * TRAIN_ROIS + s) * 4;
        dd[0] = d0; dd[1] = d1; dd[2] = d2; dd[3] = d3;
    }
}

// ---------------- kernel 2: bilinear crop-resize of GT masks ----------------
__global__ void k_mask(const float* __restrict__ proposals,
                       const void* __restrict__ masks,
                       const int* __restrict__ posmap,
                       const int* __restrict__ flag,
                       float* __restrict__ out_mask) {
#pragma clang fp contract(off)
    int s = blockIdx.x;   // 0..199
    int b = blockIdx.y;
    float* o = out_mask + (long long)(b * TRAIN_ROIS + s) * (MASK_H * MASK_W);
    int pi = -1, pg = 0;
    if (s < NUM_POS) {
        pi = posmap[(b * NUM_POS + s) * 2 + 0];
        pg = posmap[(b * NUM_POS + s) * 2 + 1];
    }
    if (pi < 0) {
        for (int p = threadIdx.x; p < MASK_H * MASK_W; p += blockDim.x) o[p] = 0.f;
        return;
    }
    int f = *flag;
    const float* box = proposals + (b * Nn + pi) * 4;
    float y1 = box[0], x1 = box[1], y2 = box[2], x2 = box[3];
    for (int p = threadIdx.x; p < MASK_H * MASK_W; p += blockDim.x) {
        int py = p / MASK_W, px = p % MASK_W;
        float fy = (float)py / (float)(MASK_H - 1);
        float fx = (float)px / (float)(MASK_W - 1);
        float ys = y1 * (float)(Hm - 1) + (fy * (y2 - y1)) * (float)(Hm - 1);
        ys = fminf(fmaxf(ys, 0.f), (float)(Hm - 1));
        float xs = x1 * (float)(Wm - 1) + (fx * (x2 - x1)) * (float)(Wm - 1);
        xs = fminf(fmaxf(xs, 0.f), (float)(Wm - 1));
        int y0 = min(max((int)floorf(ys), 0), Hm - 2);
        int x0 = min(max((int)floorf(xs), 0), Wm - 2);
        float wy = ys - (float)y0;
        float wx = xs - (float)x0;
        long long i00 = ((long long)(b * Hm + y0) * Wm + x0) * Gn + pg;
        long long i01 = i00 + Gn;
        long long i10 = i00 + (long long)Wm * Gn;
        long long i11 = i10 + Gn;
        float c00, c01, c10, c11;
        if (f == 0) {
            const int* mi = (const int*)masks;
            c00 = (float)mi[i00]; c01 = (float)mi[i01];
            c10 = (float)mi[i10]; c11 = (float)mi[i11];
        } else if (f == 1) {
            const unsigned char* mu = (const unsigned char*)masks;
            c00 = (float)mu[i00]; c01 = (float)mu[i01];
            c10 = (float)mu[i10]; c11 = (float)mu[i11];
        } else {
            const float* mf = (const float*)masks;
            c00 = mf[i00]; c01 = mf[i01];
            c10 = mf[i10]; c11 = mf[i11];
        }
        float top = c00 * (1.f - wx) + c01 * wx;
        float bot = c10 * (1.f - wx) + c11 * wx;
        float v = top * (1.f - wy) + bot * wy;
        o[p] = rintf(v);   // round half to even == jnp.round
    }
}

extern "C" void kernel_launch(void* const* d_in, const int* in_sizes, int n_in,
                              void* d_out, int out_size, void* d_ws, size_t ws_size,
                              hipStream_t stream) {
    const float* proposals = (const float*)d_in[0];
    const int* class_ids = (const int*)d_in[1];
    const float* gt_boxes = (const float*)d_in[2];
    const void* masks = d_in[3];
    float* out = (float*)d_out;

    char* ws = (char*)d_ws;
    int* posmap = (int*)ws;                              // B*66*2 ints
    int* flag = (int*)(ws + Bn * NUM_POS * 2 * 4);

    k_select<<<dim3(Bn), 1024, 0, stream>>>(proposals, class_ids, gt_boxes,
                                            (const unsigned int*)masks,
                                            posmap, flag, out);
    float* out_mask = out + Bn * TRAIN_ROIS * 4 + Bn * TRAIN_ROIS + Bn * TRAIN_ROIS * 4;
    k_mask<<<dim3(TRAIN_ROIS, Bn), 256, 0, stream>>>(proposals, masks, posmap,
                                                     flag, out_mask);
}